// Round 1
// 259.370 us; speedup vs baseline: 1.2609x; 1.2609x over previous
//
#include <hip/hip_runtime.h>
#include <stdint.h>

#define DIM   2048
#define LSEQ  2048
#define BATCH 2
#define NH    32
#define NKV   8
#define HD    64
#define M_ROWS (BATCH*LSEQ)       // 4096
#define NQKV  (DIM + 2*NKV*HD)    // 3072
#define KOFF  DIM                 // 2048
#define VOFF  (DIM + NKV*HD)      // 2560

typedef __attribute__((ext_vector_type(8))) __bf16 bf16x8;
typedef __attribute__((ext_vector_type(8))) unsigned short u16x8;
typedef __attribute__((ext_vector_type(4))) float f32x4;

__device__ __forceinline__ unsigned short f2bf(float f) {
  union { float f; unsigned u; } v; v.f = f;
  unsigned u = v.u;
  u += 0x7fff + ((u >> 16) & 1);   // RNE
  return (unsigned short)(u >> 16);
}
__device__ __forceinline__ float bf2f(unsigned short h) {
  union { unsigned u; float f; } v; v.u = ((unsigned)h) << 16;
  return v.f;
}

__device__ __forceinline__ void gload_lds16(const void* g, void* l) {
  __builtin_amdgcn_global_load_lds(
      (__attribute__((address_space(1))) unsigned int*)g,
      (__attribute__((address_space(3))) unsigned int*)l, 16, 0, 0);
}

// ---------------- fp32 -> bf16 convert (vectorized) ----------------
__global__ void k_cvt_x(const float* __restrict__ in, unsigned short* __restrict__ out, int n4) {
  int i = blockIdx.x * blockDim.x + threadIdx.x;
  if (i >= n4) return;
  float4 v = ((const float4*)in)[i];
  ushort4 o;
  o.x = f2bf(v.x); o.y = f2bf(v.y); o.z = f2bf(v.z); o.w = f2bf(v.w);
  ((ushort4*)out)[i] = o;
}

// ---------------- transpose + cast: out[n][k] = bf16(in[k][n]) ----------------
__global__ void k_transpose_bf16(const float* __restrict__ in, unsigned short* __restrict__ out,
                                 int K, int N) {
  __shared__ float tile[32][33];
  int n0 = blockIdx.x * 32, k0 = blockIdx.y * 32;
  int tx = threadIdx.x, ty = threadIdx.y;
  #pragma unroll
  for (int i = ty; i < 32; i += 8)
    tile[i][tx] = in[(long)(k0 + i) * N + n0 + tx];
  __syncthreads();
  #pragma unroll
  for (int i = ty; i < 32; i += 8)
    out[(long)(n0 + i) * K + k0 + tx] = f2bf(tile[tx][i]);
}

// ---------------- transpose V section of qkv -> vT[b*512 + g*64 + d][l] ----------------
__global__ void k_transpose_v(const unsigned short* __restrict__ qkv,
                              unsigned short* __restrict__ vT) {
  __shared__ unsigned short tile[32][33];
  int c0 = blockIdx.x * 32;   // within 512 (= g*64+d)
  int l0 = blockIdx.y * 32;
  int b  = blockIdx.z;
  int tx = threadIdx.x, ty = threadIdx.y;
  #pragma unroll
  for (int i = ty; i < 32; i += 8)
    tile[i][tx] = qkv[((long)b * LSEQ + l0 + i) * NQKV + VOFF + c0 + tx];
  __syncthreads();
  #pragma unroll
  for (int i = ty; i < 32; i += 8)
    vT[((long)b * 512 + c0 + i) * LSEQ + l0 + tx] = tile[tx][i];
}

// ---------------- RoPE tables ----------------
__global__ void k_rope_table(float* __restrict__ cosT, float* __restrict__ sinT) {
  int i = blockIdx.x * 256 + threadIdx.x;  // < LSEQ*32
  int t = i >> 5, j = i & 31;
  float inv = powf(10000.0f, -(float)j / 32.0f);
  float fr = (float)t * inv;
  cosT[i] = cosf(fr);
  sinT[i] = sinf(fr);
}

// ---------------- RoPE apply in-place on qkv (Q: 32 heads, K: 8 heads) ----------------
__global__ void k_rope_apply(unsigned short* __restrict__ qkv, const float* __restrict__ cosT,
                             const float* __restrict__ sinT) {
  long i = (long)blockIdx.x * 256 + threadIdx.x;  // < M_ROWS*40*32
  int j = (int)(i & 31);
  long rem = i >> 5;
  int hs = (int)(rem % 40);
  long row = rem / 40;
  int t = (int)(row & (LSEQ - 1));
  long col = (hs < 32) ? (long)hs * 64 + j : (long)KOFF + (long)(hs - 32) * 64 + j;
  long base = row * NQKV + col;
  float v0 = bf2f(qkv[base]), v1 = bf2f(qkv[base + 32]);
  float c = cosT[t * 32 + j], s = sinT[t * 32 + j];
  qkv[base]      = f2bf(v0 * c - v1 * s);
  qkv[base + 32] = f2bf(v1 * c + v0 * s);
}

// ---------------- GEMM: C[M,N] = A[M,K](bf16) * Bt[N,K]^T(bf16), m97 structure ----------------
template<bool BF16OUT>
__global__ __launch_bounds__(256) void k_gemm_bt(
    const unsigned short* __restrict__ A, const unsigned short* __restrict__ Bt,
    void* __restrict__ Cv, int M, int N, int K) {
  __shared__ unsigned short As[128 * 32];
  __shared__ unsigned short Bs[128 * 32];
  int t = threadIdx.x;
  int lane = t & 63, wave = t >> 6;
  int fr = lane & 15, fg = lane >> 4;
  long rowA = (long)blockIdx.x * 128;
  long rowB = (long)blockIdx.y * 128;
  const unsigned short* Ap  = A  + (rowA + (t >> 2)) * (long)K + (t & 3) * 8;
  const unsigned short* Ap2 = Ap + 64 * (long)K;
  const unsigned short* Bp  = Bt + (rowB + (t >> 2)) * (long)K + (t & 3) * 8;
  const unsigned short* Bp2 = Bp + 64 * (long)K;
  f32x4 acc[4][4] = {};
  int wr = (wave >> 1) * 64, wc = (wave & 1) * 64;
  char* AsB = (char*)As; char* BsB = (char*)Bs;
  for (int kt = 0; kt < K; kt += 32) {
    gload_lds16(Ap + kt,  AsB + t * 16);
    gload_lds16(Ap2 + kt, AsB + 4096 + t * 16);
    gload_lds16(Bp + kt,  BsB + t * 16);
    gload_lds16(Bp2 + kt, BsB + 4096 + t * 16);
    __syncthreads();
    bf16x8 af[4], bfv[4];
    #pragma unroll
    for (int i = 0; i < 4; i++)
      af[i] = *(const bf16x8*)(AsB + (wr + i * 16 + fr) * 64 + fg * 16);
    #pragma unroll
    for (int j = 0; j < 4; j++)
      bfv[j] = *(const bf16x8*)(BsB + (wc + j * 16 + fr) * 64 + fg * 16);
    #pragma unroll
    for (int i = 0; i < 4; i++) {
      #pragma unroll
      for (int j = 0; j < 4; j++)
        acc[i][j] = __builtin_amdgcn_mfma_f32_16x16x32_bf16(af[i], bfv[j], acc[i][j], 0, 0, 0);
    }
    __syncthreads();
  }
  #pragma unroll
  for (int i = 0; i < 4; i++) {
    #pragma unroll
    for (int j = 0; j < 4; j++) {
      #pragma unroll
      for (int r = 0; r < 4; r++) {
        long row = rowA + wr + i * 16 + fg * 4 + r;
        long col = rowB + wc + j * 16 + fr;
        if (BF16OUT) ((unsigned short*)Cv)[row * N + col] = f2bf(acc[i][j][r]);
        else         ((float*)Cv)[row * N + col] = acc[i][j][r];
      }
    }
  }
}

// ---------------- softmax + P staging, NS k-subtiles (per 16q x NS*16k subtile) ----------------
// st[s][r]: lane (fr,fg) holds S[q = qbase + fg*4+r][kpos = kbase + s*16+fr].
// exp2-domain: C2 = 0.125*log2(e); m tracked in that domain.
// l is PER-LANE PARTIAL (this lane's 8 kp slots only) -- reduce over fr group at epilogue.
template<int NS>
__device__ __forceinline__ void softmax_ns(
    f32x4* st, float* m, float* l, f32x4* po, char* PlSub, int fr, int fg) {
  const float C2 = 0.125f * 1.44269504f;
  #pragma unroll
  for (int r = 0; r < 4; r++) {
    float mx = st[0][r];
    #pragma unroll
    for (int s = 1; s < NS; s++) mx = fmaxf(mx, st[s][r]);
    #pragma unroll
    for (int off = 1; off < 16; off <<= 1) mx = fmaxf(mx, __shfl_xor(mx, off, 64));
    mx *= C2;
    float mn = fmaxf(m[r], mx);
    float sc = exp2f(m[r] - mn);
    float P[NS];
    float rs = 0.f;
    #pragma unroll
    for (int s = 0; s < NS; s++) { P[s] = exp2f(st[s][r] * C2 - mn); rs += P[s]; }
    #pragma unroll
    for (int dt = 0; dt < 4; dt++) po[dt][r] *= sc;
    l[r] = l[r] * sc + rs;   // per-lane partial
    m[r] = mn;
    int qr = fg * 4 + r;
    #pragma unroll
    for (int s = 0; s < NS; s++) {
      int kp = s * 16 + fr;
      *(unsigned short*)(PlSub + qr * (NS * 32) + ((kp * 2) ^ ((qr & 7) << 4))) = f2bf(P[s]);
    }
  }
}

// ---------------- flash attention v10: LDS-staged K/V with prefetch-under-PV ----------------
// grid: 1024 = qt(16, heavy-first) x hb(64, fastest -> XCD spread); block 256 = 4 waves.
// Round-12 theory: v9 was load-latency-bound (~12K cyc/wave-iter vs ~3K compute; MfmaUtil 8.4%,
// VALUBusy 38%, all pipes idle) -- 32 per-wave global K/V loads per iter, 4x redundant across
// waves, serialized by VGPR pressure. Fix: stage K(16KB,single-buf) + V(16KB,double-buf) via
// async global_load_lds, issued for kt+1 right after the post-softmax barrier (K reads done
// there; V reads use the other buffer) so HBM/L2 latency hides under PV. XOR-swizzled LDS
// (linear gload dest + inverse-swizzled global src + swizzled ds_read_b128) per G4/G21.
// LDS 80KB/block -> 2 resident blocks/CU + 2 backfill.
__global__ __launch_bounds__(256, 2) void k_flash_attn7(
    const unsigned short* __restrict__ qkv, const unsigned short* __restrict__ vT,
    unsigned short* __restrict__ attn) {
  int g0 = (int)blockIdx.x;
  int hb = g0 & 63;
  int h = hb & 31, b = hb >> 5;
  int qt = 15 - (g0 >> 6);            // heavy blocks first (backfill smooths the tail)
  int g = h >> 2;
  int t = threadIdx.x, lane = t & 63, wave = t >> 6;
  int fr = lane & 15, fg = lane >> 4;

  __shared__ __align__(16) unsigned short Pl[4][4096];  // 32KB: [wave][A 16x128 | B 16x128]
  __shared__ __align__(16) char KT[16384];              // 16KB: K tile [128 rows][128B], swz
  __shared__ __align__(16) char VT2[2][16384];          // 32KB: V tile [64 rows][256B], swz, dbuf
  char* PlW = (char*)&Pl[wave][0];
  long rowbase = (long)b * LSEQ;

  int qbaseA = qt * 128 + wave * 32;
  int qbaseB = qbaseA + 16;

  const unsigned short* qpA = &qkv[(rowbase + qbaseA + fr) * NQKV + h * 64 + fg * 8];
  const unsigned short* qpB = &qkv[(rowbase + qbaseB + fr) * NQKV + h * 64 + fg * 8];
  bf16x8 qfA0 = *(const bf16x8*)(qpA);
  bf16x8 qfA1 = *(const bf16x8*)(qpA + 32);
  bf16x8 qfB0 = *(const bf16x8*)(qpB);
  bf16x8 qfB1 = *(const bf16x8*)(qpB + 32);

  // staging source column-bytes (inverse swizzle; row&7 == derived-from-t bits since
  // chunk row offsets are multiples of 8)
  int kcb = ((t & 7) * 16) ^ (((t >> 3) & 7) << 4);    // K: 128B rows, row = p*32 + (t>>3)
  int vcb = ((t & 15) * 16) ^ (((t >> 4) & 7) << 4);   // V: 256B rows, row = p*16 + (t>>4)

  const char* kgb = (const char*)qkv;
  const char* vgb = (const char*)vT;
  long ksrc0 = ((rowbase) * (long)NQKV + KOFF + (long)g * 64) * 2;  // + (kbase+krow)*NQKV*2 + kcb
  long vsrc0 = (((long)(b * 512 + g * 64)) * LSEQ) * 2;            // + vrow*LSEQ*2 + kbase*2 + vcb

  auto stageK = [&](int kbase) {
    #pragma unroll
    for (int p = 0; p < 4; p++) {
      int krow = p * 32 + (t >> 3);
      gload_lds16(kgb + ksrc0 + (long)(kbase + krow) * (NQKV * 2) + kcb,
                  KT + p * 4096 + t * 16);
    }
  };
  auto stageV = [&](int kbase, char* dst) {
    #pragma unroll
    for (int p = 0; p < 4; p++) {
      int vrow = p * 16 + (t >> 4);
      gload_lds16(vgb + vsrc0 + (long)vrow * (LSEQ * 2) + kbase * 2 + vcb,
                  dst + p * 4096 + t * 16);
    }
  };

  stageK(0);
  stageV(0, VT2[0]);

  f32x4 poA[4] = {}, poB[4] = {};
  float mA[4], lA[4], mB[4], lB[4];
  #pragma unroll
  for (int r = 0; r < 4; r++) { mA[r] = -1e30f; lA[r] = 0.f; mB[r] = -1e30f; lB[r] = 0.f; }

  int sw8 = (fr & 7) << 4;

  for (int kt = 0; kt <= qt; kt++) {
    int kbase = kt * 128;
    __syncthreads();   // B1: staged K/V landed (vmcnt drained); prev iter's LDS reads done

    f32x4 stA[8], stB[8];
    __builtin_amdgcn_s_setprio(1);
    #pragma unroll
    for (int s = 0; s < 8; s++) {
      const char* kr = KT + ((s * 16 + fr) << 7);
      bf16x8 kf0 = *(const bf16x8*)(kr + ((fg * 16) ^ sw8));
      bf16x8 kf1 = *(const bf16x8*)(kr + ((fg * 16 + 64) ^ sw8));
      f32x4 a = {};
      a = __builtin_amdgcn_mfma_f32_16x16x32_bf16(qfA0, kf0, a, 0, 0, 0);
      a = __builtin_amdgcn_mfma_f32_16x16x32_bf16(qfA1, kf1, a, 0, 0, 0);
      stA[s] = a;
      f32x4 c = {};
      c = __builtin_amdgcn_mfma_f32_16x16x32_bf16(qfB0, kf0, c, 0, 0, 0);
      c = __builtin_amdgcn_mfma_f32_16x16x32_bf16(qfB1, kf1, c, 0, 0, 0);
      stB[s] = c;
    }
    __builtin_amdgcn_s_setprio(0);

    if (kt == qt) {   // only the diagonal 128-tile needs masking
      #pragma unroll
      for (int s = 0; s < 8; s++) {
        #pragma unroll
        for (int r = 0; r < 4; r++) {
          if (kbase + s * 16 + fr > qbaseA + fg * 4 + r) stA[s][r] = -1e30f;
          if (kbase + s * 16 + fr > qbaseB + fg * 4 + r) stB[s][r] = -1e30f;
        }
      }
    }

    softmax_ns<8>(stA, mA, lA, poA, PlW, fr, fg);
    softmax_ns<8>(stB, mB, lB, poB, PlW + 4096, fr, fg);
    __syncthreads();   // B2: P visible; all waves' K reads complete

    // prefetch next tile under PV: K reuse is WAR-safe past B2; V goes to the other buffer
    if (kt < qt) {
      stageK(kbase + 128);
      stageV(kbase + 128, VT2[(kt + 1) & 1]);
    }

    const char* Vb = VT2[kt & 1];
    __builtin_amdgcn_s_setprio(1);
    #pragma unroll
    for (int km = 0; km < 4; km++) {
      bf16x8 pfA = *(const bf16x8*)(PlW + fr * 256 + ((km * 64 + fg * 16) ^ sw8));
      bf16x8 pfB = *(const bf16x8*)(PlW + 4096 + fr * 256 + ((km * 64 + fg * 16) ^ sw8));
      #pragma unroll
      for (int dt = 0; dt < 4; dt++) {
        const char* vr = Vb + ((dt * 16 + fr) << 8);
        bf16x8 vf = *(const bf16x8*)(vr + ((km * 64 + fg * 16) ^ sw8));
        poA[dt] = __builtin_amdgcn_mfma_f32_16x16x32_bf16(pfA, vf, poA[dt], 0, 0, 0);
        poB[dt] = __builtin_amdgcn_mfma_f32_16x16x32_bf16(pfB, vf, poB[dt], 0, 0, 0);
      }
    }
    __builtin_amdgcn_s_setprio(0);
    // no trailing barrier: B1 of the next iteration orders LDS reads vs. restaging
  }

  // reduce per-lane partial l over the 16-lane fr group (row = fg*4+r uniform there)
  #pragma unroll
  for (int r = 0; r < 4; r++) {
    #pragma unroll
    for (int off = 1; off < 16; off <<= 1) {
      lA[r] += __shfl_xor(lA[r], off, 64);
      lB[r] += __shfl_xor(lB[r], off, 64);
    }
  }

  #pragma unroll
  for (int dt = 0; dt < 4; dt++) {
    #pragma unroll
    for (int r = 0; r < 4; r++) {
      attn[(rowbase + qbaseA + fg * 4 + r) * DIM + h * 64 + dt * 16 + fr] = f2bf(poA[dt][r] / lA[r]);
      attn[(rowbase + qbaseB + fg * 4 + r) * DIM + h * 64 + dt * 16 + fr] = f2bf(poB[dt][r] / lB[r]);
    }
  }
}

extern "C" void kernel_launch(void* const* d_in, const int* in_sizes, int n_in,
                              void* d_out, int out_size, void* d_ws, size_t ws_size,
                              hipStream_t stream) {
  const float* x  = (const float*)d_in[0];
  const float* wq = (const float*)d_in[1];
  const float* wk = (const float*)d_in[2];
  const float* wv = (const float*)d_in[3];
  const float* wo = (const float*)d_in[4];

  char* ws = (char*)d_ws;
  unsigned short* xb    = (unsigned short*)(ws);                 // 16.78 MB (reused as vT later)
  unsigned short* wqkvT = (unsigned short*)(ws + 16777216);      // 12.58 MB [3072][2048]
  unsigned short* woT   = (unsigned short*)(ws + 29360128);      //  8.39 MB [2048][2048]
  unsigned short* qkv   = (unsigned short*)(ws + 37748736);      // 25.17 MB [4096][3072]
  unsigned short* attn  = (unsigned short*)(ws + 62914560);      // 16.78 MB [4096][2048]
  float* cosT           = (float*)(ws + 79691776);               // 256 KB
  float* sinT           = (float*)(ws + 79953920);               // 256 KB
  unsigned short* vT    = xb;                                    // alias: xb dead after QKV GEMM

  k_cvt_x<<<8192, 256, 0, stream>>>(x, xb, M_ROWS * DIM / 4);
  dim3 tb(32, 8);
  k_transpose_bf16<<<dim3(DIM/32, DIM/32), tb, 0, stream>>>(wq, wqkvT, DIM, DIM);
  k_transpose_bf16<<<dim3(512/32, DIM/32), tb, 0, stream>>>(wk, wqkvT + (long)2048*2048, DIM, 512);
  k_transpose_bf16<<<dim3(512/32, DIM/32), tb, 0, stream>>>(wv, wqkvT + (long)2560*2048, DIM, 512);
  k_transpose_bf16<<<dim3(DIM/32, DIM/32), tb, 0, stream>>>(wo, woT, DIM, DIM);
  k_rope_table<<<(LSEQ*32)/256, 256, 0, stream>>>(cosT, sinT);

  k_gemm_bt<true><<<dim3(M_ROWS/128, NQKV/128), 256, 0, stream>>>(xb, wqkvT, qkv, M_ROWS, NQKV, DIM);
  k_rope_apply<<<(M_ROWS*40*32)/256, 256, 0, stream>>>(qkv, cosT, sinT);
  k_transpose_v<<<dim3(16, 64, 2), tb, 0, stream>>>(qkv, vT);
  k_flash_attn7<<<1024, 256, 0, stream>>>(qkv, vT, attn);
  k_gemm_bt<false><<<dim3(M_ROWS/128, DIM/128), 256, 0, stream>>>(attn, woT, d_out, M_ROWS, DIM, DIM);
}